// Round 7
// baseline (44.382 us; speedup 1.0000x reference)
//
#include <hip/hip_runtime.h>
#include <math.h>

#define LL 4096
#define BB 2048
#define NT 256
#define NW (NT / 64)
#define ALPHA 1.0f
#define BETA 0.5f
#define NEG_INF (-__builtin_inff())
#define POS_INF (__builtin_inff())

// Buffer: 262 chunks of 8 elems (+1 pad dword) covering global chunks
// [256p-3, 256p+258]. Chunk k (buffer index k+3) at dwords 9*(k+3)+0..7.
// Relative offset from own-chunk base for logical delta d (arith shr = floor):
#define BSZ (262 * 9)
#define OFS2(d) (9 * ((d) >> 3) + ((d) & 7))

// ---- DPP wave64 sum reduction (VALU pipe) ----
template <int CTRL, int RM>
__device__ __forceinline__ float dpp_addf(float v) {
    int s = __builtin_amdgcn_update_dpp(0, __float_as_int(v), CTRL, RM, 0xf, true);
    return v + __int_as_float(s);
}
__device__ __forceinline__ float wredf(float v) {
    v = dpp_addf<0x111, 0xf>(v);   // row_shr:1
    v = dpp_addf<0x112, 0xf>(v);   // row_shr:2
    v = dpp_addf<0x114, 0xf>(v);   // row_shr:4
    v = dpp_addf<0x118, 0xf>(v);   // row_shr:8
    v = dpp_addf<0x142, 0xa>(v);   // row_bcast:15
    v = dpp_addf<0x143, 0xc>(v);   // row_bcast:31
    return v;                      // total in lane 63
}

__global__ __launch_bounds__(NT, 8) void row_kernel(const float* __restrict__ gA,
                                                    const float* __restrict__ gB,
                                                    float4* __restrict__ rowout) {
    __shared__ float bS[BSZ];      // suffix-max within 8-aligned chunk
    __shared__ float bP[BSZ];      // prefix-max within 8-aligned chunk
    __shared__ float4 red4[NW];
    __shared__ float  redp[NW];
    __shared__ int    redc[NW][2];

    const int b = blockIdx.x;
    const int t = threadIdx.x;
    const float* rowA = gA + (size_t)b * LL;
    const float* rowB = gB + (size_t)b * LL;
    float* const Sb = bS + 9 * (t + 3);        // own eval-chunk base
    float* const Pb = bP + 9 * (t + 3);
    const int kh = (t < 3) ? (t - 3) : (253 + t);   // halo buffer chunk (t<6)
    float* const Sh = bS + 9 * (kh + 3);
    float* const Ph = bP + 9 * (kh + 3);

    float se = 0.f, dtp = 0.f, na = 0.f, nb = 0.f, p2p = 0.f;
    int cntA = 0, cntB = 0;        // wave-uniform (ballot/popc), SALU pipe

    auto scan_store = [](const float (&x)[8], float* S, float* P) {
        float pp[8], ss[8];
        pp[0] = x[0];
#pragma unroll
        for (int j = 1; j < 8; ++j) pp[j] = fmaxf(pp[j - 1], x[j]);
        ss[7] = x[7];
#pragma unroll
        for (int j = 6; j >= 0; --j) ss[j] = fmaxf(ss[j + 1], x[j]);
#pragma unroll
        for (int j = 0; j < 8; ++j) { P[j] = pp[j]; S[j] = ss[j]; }
        return pp[7];              // chunk max
    };

    auto halo_scan = [&](const float* row, int p) {
        if (t < 6) {
            float hx[8];
            const int gh = 256 * p + kh;           // global chunk
            if (gh >= 0 && gh < 512) {
                const float4* h4 = (const float4*)(row + gh * 8);
                float4 u0 = h4[0], u1 = h4[1];
                hx[0] = u0.x; hx[1] = u0.y; hx[2] = u0.z; hx[3] = u0.w;
                hx[4] = u1.x; hx[5] = u1.y; hx[6] = u1.z; hx[7] = u1.w;
            } else {
#pragma unroll
                for (int j = 0; j < 8; ++j) hx[j] = NEG_INF;
            }
            scan_store(hx, Sh, Ph);
        }
    };

    auto evalsig = [&](const float (&x)[8], float cmax, int p, unsigned& m10, int& cnt) {
        const float Cm2 = Pb[OFS2(-9)];
        const float Cm1 = Pb[OFS2(-1)];
        const float Cp1 = Pb[OFS2(15)];
        const float Cp2 = Pb[OFS2(23)];
        const float f1 = fmaxf(Cm1, cmax);
        const float f2 = fmaxf(cmax, Cp1);
        const float g2 = fmaxf(f1, Cp1);
        const float g1 = fmaxf(g2, Cm2);
        const float g3 = fmaxf(g2, Cp2);
        const float xm1 = (p == 0 && t == 0)      ? POS_INF : Sb[OFS2(-1)];
        const float xp1 = (p == 1 && t == NT - 1) ? POS_INF : Pb[OFS2(8)];
        m10 = 0u;
#pragma unroll
        for (int j = 0; j < 8; ++j) {
            float xi = x[j];
            float xl = (j > 0) ? x[j - 1] : xm1;
            float xr = (j < 7) ? x[j + 1] : xp1;
            bool lm = (xi > xl) && (xi > xr);
            float a19 = Sb[OFS2(j - 9)];
            float b19 = Pb[OFS2(j + 9)];
            float a39 = Sb[OFS2(j - 19)];
            float b39 = Pb[OFS2(j + 19)];
            float mid19 = (j == 0) ? f1 : ((j == 7) ? f2 : cmax);
            float mid39 = (j <= 2) ? g1 : ((j <= 4) ? g2 : g3);
            float p19 = fmaxf(fmaxf(a19, b19), mid19);
            float p39 = fmaxf(fmaxf(a39, b39), mid39);
            if (lm && xi >= p19) m10 |= (1u << j);
            unsigned long long bal = __ballot(lm && (xi >= p39));
            cnt += (int)__popcll(bal);     // wave-uniform SALU accumulate
        }
    };

#pragma unroll
    for (int p = 0; p < 2; ++p) {
        const float* rA = rowA + 2048 * p;
        const float* rB = rowB + 2048 * p;
        float xA[8], xB[8];
        {
            const float4* a4 = (const float4*)rA;
            const float4* b4 = (const float4*)rB;
            float4 v0 = a4[2 * t], v1 = a4[2 * t + 1];
            xA[0] = v0.x; xA[1] = v0.y; xA[2] = v0.z; xA[3] = v0.w;
            xA[4] = v1.x; xA[5] = v1.y; xA[6] = v1.z; xA[7] = v1.w;
            float4 u0 = b4[2 * t], u1 = b4[2 * t + 1];
            xB[0] = u0.x; xB[1] = u0.y; xB[2] = u0.z; xB[3] = u0.w;
            xB[4] = u1.x; xB[5] = u1.y; xB[6] = u1.z; xB[7] = u1.w;
        }
#pragma unroll
        for (int j = 0; j < 8; ++j) {
            float d = xA[j] - xB[j];
            se  += d * d;
            dtp += xA[j] * xB[j];
            na  += xA[j] * xA[j];
            nb  += xB[j] * xB[j];
        }

        unsigned mA, mB;
        // --- signal A ---
        float cmA = scan_store(xA, Sb, Pb);
        halo_scan(rowA, p);
        __syncthreads();
        evalsig(xA, cmA, p, mA, cntA);
        __syncthreads();
        // --- signal B ---
        float cmB = scan_store(xB, Sb, Pb);
        halo_scan(rowB, p);
        __syncthreads();
        evalsig(xB, cmB, p, mB, cntB);

        // peak-to-peak squared error for this phase (registers only)
#pragma unroll
        for (int j = 0; j < 8; ++j) {
            float av = ((mA >> j) & 1u) ? xA[j] : 0.f;
            float bv = ((mB >> j) & 1u) ? xB[j] : 0.f;
            float d = av - bv;
            p2p += d * d;
        }
        if (p == 0) __syncthreads();   // protect buffers before phase-2 scan
    }

    // ---- tail reductions: 5 DPP float chains; counts already wave-uniform ----
    se = wredf(se); dtp = wredf(dtp); na = wredf(na); nb = wredf(nb); p2p = wredf(p2p);
    const int w = t >> 6;
    if ((t & 63) == 63) { red4[w] = make_float4(se, dtp, na, nb); redp[w] = p2p; }
    if ((t & 63) == 0)  { redc[w][0] = cntA; redc[w][1] = cntB; }
    __syncthreads();
    if (t == 0) {
        float s0 = 0, s1 = 0, s2 = 0, s3 = 0, s4 = 0;
        int ca = 0, cb = 0;
#pragma unroll
        for (int i = 0; i < NW; ++i) {
            float4 u = red4[i];
            s0 += u.x; s1 += u.y; s2 += u.z; s3 += u.w;
            s4 += redp[i];
            ca += redc[i][0]; cb += redc[i][1];
        }
        float mse_i = s0 / (float)LL;
        float cos_i = s1 / (sqrtf(s2) * sqrtf(s3));
        float p2p_i = s4 / (float)LL;
        float custom_i = (ca != cb) ? (mse_i * ALPHA) : (p2p_i * BETA);
        rowout[b] = make_float4(mse_i, cos_i, p2p_i, custom_i);
    }
}

__global__ __launch_bounds__(256) void reduce_kernel(const float4* __restrict__ rows,
                                                     float* __restrict__ out) {
    __shared__ float red[4][4];
    float sx = 0.f, sy = 0.f, sz = 0.f, sw = 0.f;
    for (int r = threadIdx.x; r < BB; r += 256) {
        float4 v = rows[r];
        sx += v.x; sy += v.y; sz += v.z; sw += v.w;
    }
    sx = wredf(sx); sy = wredf(sy); sz = wredf(sz); sw = wredf(sw);
    int w = threadIdx.x >> 6, lane = threadIdx.x & 63;
    if (lane == 63) { red[w][0] = sx; red[w][1] = sy; red[w][2] = sz; red[w][3] = sw; }
    __syncthreads();
    if (threadIdx.x == 0) {
        float ax = 0, ay = 0, az = 0, aw = 0;
        for (int i = 0; i < 4; ++i) {
            ax += red[i][0]; ay += red[i][1]; az += red[i][2]; aw += red[i][3];
        }
        float mse = ax / (float)BB;
        out[0] = mse + aw;          // total_loss = mse_loss + custom_loss
        out[1] = ay / (float)BB;    // mean cosine similarity
        out[2] = az;                // p2p_loss
        out[3] = mse;               // mse_loss
    }
}

extern "C" void kernel_launch(void* const* d_in, const int* in_sizes, int n_in,
                              void* d_out, int out_size, void* d_ws, size_t ws_size,
                              hipStream_t stream) {
    const float* inA = (const float*)d_in[0];   // in_signal
    const float* inB = (const float*)d_in[1];   // ref_signal
    float* out = (float*)d_out;
    float4* rows = (float4*)d_ws;               // 2048 * 16 B scratch, fully rewritten each call

    hipLaunchKernelGGL(row_kernel, dim3(BB), dim3(NT), 0, stream, inA, inB, rows);
    hipLaunchKernelGGL(reduce_kernel, dim3(1), dim3(256), 0, stream, rows, out);
}

// Round 8
// 31.179 us; speedup vs baseline: 1.4235x; 1.4235x over previous
//
#include <hip/hip_runtime.h>
#include <math.h>

#define LL 4096
#define BB 2048
#define NT 512
#define CH 8                      // contiguous elements per thread; NT*CH == LL
#define ALPHA 1.0f
#define BETA 0.5f
#define NEG_INF (-__builtin_inff())
#define POS_INF (__builtin_inff())

// Padded LDS layout: logical position i in [-24, LL+23] lives at i + (i>>3) + 27.
// IDX(8t + d) == 9t + (d + (d>>3) + 27) -> with base = arr + 9t, every offset the
// eval needs is a compile-time immediate; lane stride 9 dwords => conflict-free.
#define SPSZ 4672                 // > IDX(LL+23) = 4660
#define OFS(d) ((d) + ((d) >> 3) + 27)

// ---- DPP wave64 sum reduction (VALU pipe, no LDS/bpermute) ----
template <int CTRL, int RM>
__device__ __forceinline__ float dpp_addf(float v) {
    int s = __builtin_amdgcn_update_dpp(0, __float_as_int(v), CTRL, RM, 0xf, true);
    return v + __int_as_float(s);
}
__device__ __forceinline__ float wredf(float v) {
    v = dpp_addf<0x111, 0xf>(v);   // row_shr:1
    v = dpp_addf<0x112, 0xf>(v);   // row_shr:2
    v = dpp_addf<0x114, 0xf>(v);   // row_shr:4
    v = dpp_addf<0x118, 0xf>(v);   // row_shr:8  -> lane15 of each row = row sum
    v = dpp_addf<0x142, 0xa>(v);   // row_bcast:15 into rows 1,3
    v = dpp_addf<0x143, 0xc>(v);   // row_bcast:31 into rows 2,3
    return v;                      // total in lane 63
}

// LDS-only barrier: waits ds ops (lgkmcnt) but does NOT drain vmcnt, so
// in-flight global prefetch loads survive across it (vs __syncthreads'
// full vmcnt(0) drain).
__device__ __forceinline__ void barrier_lds() {
    asm volatile("s_waitcnt lgkmcnt(0)" ::: "memory");
    __builtin_amdgcn_s_barrier();
}

__global__ __launch_bounds__(NT, 6) void row_kernel(const float* __restrict__ gA,
                                                    const float* __restrict__ gB,
                                                    float4* __restrict__ rowout) {
    __shared__ float sS[SPSZ];     // suffix-max within 8-aligned chunk (+ -inf margins)
    __shared__ float sP[SPSZ];     // prefix-max within 8-aligned chunk (+ -inf margins)
    __shared__ float4 red4[NT / 64][2];   // per-wave partials, float4-packed

    const int b = blockIdx.x;      // rows b and b + BB/2
    const int t = threadIdx.x;
    float* const Sb = sS + 9 * t;
    float* const Pb = sP + 9 * t;

    // ---- issue ALL loads for both rows up front (8x dwordx4 in flight) ----
    float x1A[CH], x1B[CH], x2A[CH], x2B[CH];
    {
        const float4* a1 = (const float4*)(gA + (size_t)b * LL);
        const float4* b1 = (const float4*)(gB + (size_t)b * LL);
        const float4* a2 = (const float4*)(gA + (size_t)(b + BB / 2) * LL);
        const float4* b2 = (const float4*)(gB + (size_t)(b + BB / 2) * LL);
#pragma unroll
        for (int k = 0; k < CH / 4; ++k) {
            float4 v = a1[2 * t + k];
            x1A[4 * k + 0] = v.x; x1A[4 * k + 1] = v.y; x1A[4 * k + 2] = v.z; x1A[4 * k + 3] = v.w;
        }
#pragma unroll
        for (int k = 0; k < CH / 4; ++k) {
            float4 v = b1[2 * t + k];
            x1B[4 * k + 0] = v.x; x1B[4 * k + 1] = v.y; x1B[4 * k + 2] = v.z; x1B[4 * k + 3] = v.w;
        }
#pragma unroll
        for (int k = 0; k < CH / 4; ++k) {
            float4 v = a2[2 * t + k];
            x2A[4 * k + 0] = v.x; x2A[4 * k + 1] = v.y; x2A[4 * k + 2] = v.z; x2A[4 * k + 3] = v.w;
        }
#pragma unroll
        for (int k = 0; k < CH / 4; ++k) {
            float4 v = b2[2 * t + k];
            x2B[4 * k + 0] = v.x; x2B[4 * k + 1] = v.y; x2B[4 * k + 2] = v.z; x2B[4 * k + 3] = v.w;
        }
    }

    // ---- -inf margins (logical i in [-24,-1] and [LL, LL+23]); written once ----
    if (t < 24) {
        int i = t - 24;
        int p = i + (i >> 3) + 27;
        sS[p] = NEG_INF; sP[p] = NEG_INF;
    } else if (t >= NT - 24) {
        int i = LL + (t - (NT - 24));
        int p = i + (i >> 3) + 27;
        sS[p] = NEG_INF; sP[p] = NEG_INF;
    }

    // ---- per-signal: scan -> LDS, barrier, branchless eval (all imm offsets) ----
    auto process = [&](const float (&x)[CH], int& cnt20, unsigned& m10) {
        float pp[CH], ss[CH];
        pp[0] = x[0];
#pragma unroll
        for (int j = 1; j < CH; ++j) pp[j] = fmaxf(pp[j - 1], x[j]);
        ss[CH - 1] = x[CH - 1];
#pragma unroll
        for (int j = CH - 2; j >= 0; --j) ss[j] = fmaxf(ss[j + 1], x[j]);
#pragma unroll
        for (int j = 0; j < CH; ++j) {
            Pb[j + 27] = pp[j];    // contiguous -> ds_write2_b32 pairs
            Sb[j + 27] = ss[j];
        }
        const float cmax = pp[CH - 1];
        barrier_lds();

        // neighbor chunk maxes: C(t+k) = P[last elem of chunk t+k]
        const float Cm2 = Pb[OFS(-9)];
        const float Cm1 = Pb[OFS(-1)];
        const float Cp1 = Pb[OFS(15)];
        const float Cp2 = Pb[OFS(23)];
        const float f1 = fmaxf(Cm1, cmax);
        const float f2 = fmaxf(cmax, Cp1);
        const float g2 = fmaxf(f1, Cp1);
        const float g1 = fmaxf(g2, Cm2);
        const float g3 = fmaxf(g2, Cp2);
        const float xm1 = (t == 0)      ? POS_INF : Sb[OFS(-1)];   // x[base-1]
        const float xp1 = (t == NT - 1) ? POS_INF : Pb[OFS(8)];    // x[base+8]

        cnt20 = 0; m10 = 0u;
#pragma unroll
        for (int j = 0; j < CH; ++j) {
            float xi = x[j];
            float xl = (j > 0)      ? x[j - 1] : xm1;
            float xr = (j < CH - 1) ? x[j + 1] : xp1;
            bool lm = (xi > xl) && (xi > xr);
            float a19 = Sb[OFS(j - 9)];
            float b19 = Pb[OFS(j + 9)];
            float a39 = Sb[OFS(j - 19)];
            float b39 = Pb[OFS(j + 19)];
            float mid19 = (j == 0) ? f1 : ((j == CH - 1) ? f2 : cmax);
            float mid39 = (j <= 2) ? g1 : ((j <= 4) ? g2 : g3);
            float p19 = fmaxf(fmaxf(a19, b19), mid19);
            float p39 = fmaxf(fmaxf(a39, b39), mid39);
            if (lm && xi >= p19) m10 |= (1u << j);
            if (lm && xi >= p39) cnt20++;
        }
    };

    // ---- full per-row pipeline (stats, peaks, reductions, rowout write) ----
    auto do_row = [&](const float (&xA)[CH], const float (&xB)[CH], int rowIdx) {
        float se = 0.f, dtp = 0.f, na = 0.f, nb = 0.f;
#pragma unroll
        for (int j = 0; j < CH; ++j) {
            float d = xA[j] - xB[j];
            se  += d * d;
            dtp += xA[j] * xB[j];
            na  += xA[j] * xA[j];
            nb  += xB[j] * xB[j];
        }

        int cntA, cntB;
        unsigned mA, mB;
        process(xA, cntA, mA);
        barrier_lds();             // evalA reads done before scanB overwrites
        process(xB, cntB, mB);

        float p2p = 0.f;
#pragma unroll
        for (int j = 0; j < CH; ++j) {
            float av = ((mA >> j) & 1u) ? xA[j] : 0.f;
            float bv = ((mB >> j) & 1u) ? xB[j] : 0.f;
            float d = av - bv;
            p2p += d * d;
        }

        // wave reductions on VALU (DPP); totals in lane 63
        se = wredf(se); dtp = wredf(dtp); na = wredf(na); nb = wredf(nb);
        p2p = wredf(p2p);
        float cc = wredf((float)(cntA * 4096 + cntB));   // exact: sums << 2^24
        const int w = t >> 6;
        if ((t & 63) == 63) {
            red4[w][0] = make_float4(se, dtp, na, nb);
            red4[w][1] = make_float4(p2p, cc, 0.f, 0.f);
        }
        barrier_lds();             // also protects sS/sP before next row's scan

        if (t == 0) {
            float s0 = 0, s1 = 0, s2 = 0, s3 = 0, s4 = 0, s5 = 0;
#pragma unroll
            for (int i = 0; i < NT / 64; ++i) {
                float4 u = red4[i][0];
                float4 v = red4[i][1];
                s0 += u.x; s1 += u.y; s2 += u.z; s3 += u.w;
                s4 += v.x; s5 += v.y;
            }
            int packed = (int)s5;
            int ca = packed >> 12;
            int cb = packed & 4095;
            float mse_i = s0 / (float)LL;
            float cos_i = s1 / (sqrtf(s2) * sqrtf(s3));
            float p2p_i = s4 / (float)LL;
            float custom_i = (ca != cb) ? (mse_i * ALPHA) : (p2p_i * BETA);
            rowout[rowIdx] = make_float4(mse_i, cos_i, p2p_i, custom_i);
        }
    };

    do_row(x1A, x1B, b);
    barrier_lds();                 // red4 row-1 reads (t==0) done before row-2 tail
    do_row(x2A, x2B, b + BB / 2);
}

__global__ __launch_bounds__(256) void reduce_kernel(const float4* __restrict__ rows,
                                                     float* __restrict__ out) {
    __shared__ float red[4][4];
    float sx = 0.f, sy = 0.f, sz = 0.f, sw = 0.f;
    for (int r = threadIdx.x; r < BB; r += 256) {
        float4 v = rows[r];
        sx += v.x; sy += v.y; sz += v.z; sw += v.w;
    }
    sx = wredf(sx); sy = wredf(sy); sz = wredf(sz); sw = wredf(sw);
    int w = threadIdx.x >> 6, lane = threadIdx.x & 63;
    if (lane == 63) { red[w][0] = sx; red[w][1] = sy; red[w][2] = sz; red[w][3] = sw; }
    __syncthreads();
    if (threadIdx.x == 0) {
        float ax = 0, ay = 0, az = 0, aw = 0;
        for (int i = 0; i < 4; ++i) {
            ax += red[i][0]; ay += red[i][1]; az += red[i][2]; aw += red[i][3];
        }
        float mse = ax / (float)BB;
        out[0] = mse + aw;          // total_loss = mse_loss + custom_loss
        out[1] = ay / (float)BB;    // mean cosine similarity
        out[2] = az;                // p2p_loss
        out[3] = mse;               // mse_loss
    }
}

extern "C" void kernel_launch(void* const* d_in, const int* in_sizes, int n_in,
                              void* d_out, int out_size, void* d_ws, size_t ws_size,
                              hipStream_t stream) {
    const float* inA = (const float*)d_in[0];   // in_signal
    const float* inB = (const float*)d_in[1];   // ref_signal
    float* out = (float*)d_out;
    float4* rows = (float4*)d_ws;               // 2048 * 16 B scratch, fully rewritten each call

    hipLaunchKernelGGL(row_kernel, dim3(BB / 2), dim3(NT), 0, stream, inA, inB, rows);
    hipLaunchKernelGGL(reduce_kernel, dim3(1), dim3(256), 0, stream, rows, out);
}